// Round 16
// baseline (407.679 us; speedup 1.0000x reference)
//
#include <hip/hip_runtime.h>
#include <hip/hip_bf16.h>

#define BB 16
#define NN 12
#define NE 144
#define TT 128
#define CC 128

typedef __attribute__((ext_vector_type(8))) short v8s;   // 8 x bf16
typedef __attribute__((ext_vector_type(4))) short v4s;   // 4 x bf16
typedef __attribute__((ext_vector_type(4))) float v4f;   // mfma accumulator

__device__ __forceinline__ short f2bf(float f) {
    unsigned u = __float_as_uint(f);
    u += 0x7fffu + ((u >> 16) & 1u);        // RNE
    return (short)(u >> 16);
}
__device__ __forceinline__ float bf2f(unsigned short u) {
    return __uint_as_float(((unsigned)u) << 16);
}
__device__ __forceinline__ float rndbf(float f) { return bf2f((unsigned short)f2bf(f)); }
__device__ __forceinline__ v4s f4_to_bf4(float4 a) {
    v4s r; r[0] = f2bf(a.x); r[1] = f2bf(a.y); r[2] = f2bf(a.z); r[3] = f2bf(a.w); return r;
}

// ---------------- weights -> bf16 (+ zero the epart accumulators) ----------------
__global__ __launch_bounds__(256) void kW(
    const float* A1, const float* B1, const float* E1, const float* U1, const float* V1,
    const float* A2, const float* B2, const float* E2, const float* U2, const float* V2,
    unsigned short* wb, float* epzero)
{
    int idx = blockIdx.x * 256 + threadIdx.x;   // 10*16384
    if (idx < 9216) epzero[idx] = 0.f;          // 2 layers * 2304 float2
    int w = idx >> 14, r = idx & 16383;
    const float* s;
    switch (w) {
        case 0: s = A1; break; case 1: s = B1; break; case 2: s = E1; break;
        case 3: s = U1; break; case 4: s = V1; break; case 5: s = A2; break;
        case 6: s = B2; break; case 7: s = E2; break; case 8: s = U2; break;
        default: s = V2; break;
    }
    wb[idx] = (unsigned short)f2bf(s[r]);
}

// ---------------- P: x @ {A,B,V,U}^T  -> bf16 outputs ----------------
__global__ __launch_bounds__(256) void kP(
    const float* __restrict__ x, const unsigned short* __restrict__ wb,
    int sA, int sB, int sV, int sU,
    unsigned short* __restrict__ oA, unsigned short* __restrict__ oB,
    unsigned short* __restrict__ oV, unsigned short* __restrict__ oU)
{
    __shared__ unsigned short xt[64][136];
    int tid = threadIdx.x;
    int m0 = blockIdx.x * 64;
    #pragma unroll
    for (int it = 0; it < 8; ++it) {
        int f = it * 256 + tid;
        int row = f >> 5, c4 = f & 31;
        float4 v = *reinterpret_cast<const float4*>(x + (size_t)m0 * 128 + (size_t)f * 4);
        *reinterpret_cast<v4s*>(&xt[row][c4 * 4]) = f4_to_bf4(v);
    }
    __syncthreads();
    int lane = tid & 63, wid = tid >> 6;
    int l15 = lane & 15, l4 = lane >> 4;

    const unsigned short* Ws[4] = { wb + (size_t)sA * 16384, wb + (size_t)sB * 16384,
                                    wb + (size_t)sV * 16384, wb + (size_t)sU * 16384 };
    unsigned short* Os[4] = { oA, oB, oV, oU };

    #pragma unroll
    for (int w = 0; w < 4; ++w) {
        const unsigned short* W = Ws[w];
        unsigned short* out = Os[w];
        v8s bfr[2][4];
        #pragma unroll
        for (int nt2 = 0; nt2 < 2; ++nt2) {
            int col = (wid * 2 + nt2) * 16 + l15;
            #pragma unroll
            for (int kk = 0; kk < 4; ++kk)
                bfr[nt2][kk] = *reinterpret_cast<const v8s*>(W + col * 128 + kk * 32 + l4 * 8);
        }
        v4f acc[4][2] = {};
        #pragma unroll
        for (int kk = 0; kk < 4; ++kk) {
            #pragma unroll
            for (int mt = 0; mt < 4; ++mt) {
                v8s a = *reinterpret_cast<const v8s*>(&xt[mt * 16 + l15][kk * 32 + l4 * 8]);
                acc[mt][0] = __builtin_amdgcn_mfma_f32_16x16x32_bf16(a, bfr[0][kk], acc[mt][0], 0, 0, 0);
                acc[mt][1] = __builtin_amdgcn_mfma_f32_16x16x32_bf16(a, bfr[1][kk], acc[mt][1], 0, 0, 0);
            }
        }
        #pragma unroll
        for (int mt = 0; mt < 4; ++mt) {
            #pragma unroll
            for (int nt2 = 0; nt2 < 2; ++nt2) {
                int col = (wid * 2 + nt2) * 16 + l15;
                #pragma unroll
                for (int reg = 0; reg < 4; ++reg) {
                    int rowg = m0 + mt * 16 + l4 * 4 + reg;
                    out[(size_t)rowg * 128 + col] = (unsigned short)f2bf(acc[mt][nt2][reg]);
                }
            }
        }
    }
}

// ---------------- A: wave-autonomous edge_upd stats (ZERO barriers) ----------------
// Each wave owns one (b, e, 16-t) tile in its private LDS segment. Stats are
// accumulated per-lane from the MFMA accumulator + direct xa/xb loads, reduced
// by wave shfl, and atomically added to the per-(b,e) global accumulator.
template<bool IN_F32>
__global__ __launch_bounds__(256, 4) void kA(
    const float* __restrict__ ef32, const unsigned short* __restrict__ ebf_in,
    unsigned short* __restrict__ ebf_out,
    const unsigned short* __restrict__ xAp, const unsigned short* __restrict__ xBp,
    const unsigned short* __restrict__ Ebf, float* __restrict__ epart)
{
    __shared__ unsigned short et[4][16][136];
    int tid = threadIdx.x;
    int wid = tid >> 6, lane = tid & 63;
    int gwave = blockIdx.x * 4 + wid;      // 18432 wave-tiles
    int tq = gwave & 7; int m = gwave >> 3;
    int e = m % NE, b = m / NE;
    int iA = e / 12, jA = e - iA * 12;
    int t0 = tq * 16;
    size_t erow0 = ((size_t)(b * NE + e) * TT + t0) * CC;
    unsigned short (*myet)[136] = et[wid];

    int srow = lane >> 4, c8 = lane & 15;
    if constexpr (IN_F32) {
        #pragma unroll
        for (int it = 0; it < 4; ++it) {
            int row = srow + it * 4;
            const float* p = ef32 + erow0 + (size_t)row * CC + c8 * 8;
            float4 f0 = *reinterpret_cast<const float4*>(p);
            float4 f1 = *reinterpret_cast<const float4*>(p + 4);
            v8s bv;
            bv[0] = f2bf(f0.x); bv[1] = f2bf(f0.y); bv[2] = f2bf(f0.z); bv[3] = f2bf(f0.w);
            bv[4] = f2bf(f1.x); bv[5] = f2bf(f1.y); bv[6] = f2bf(f1.z); bv[7] = f2bf(f1.w);
            *reinterpret_cast<v8s*>(&myet[row][c8 * 8]) = bv;
            *reinterpret_cast<v8s*>(ebf_out + erow0 + (size_t)row * CC + c8 * 8) = bv;
        }
    } else {
        #pragma unroll
        for (int it = 0; it < 4; ++it) {
            int row = srow + it * 4;
            *reinterpret_cast<v8s*>(&myet[row][c8 * 8]) =
                *reinterpret_cast<const v8s*>(ebf_in + erow0 + (size_t)row * CC + c8 * 8);
        }
    }
    // no __syncthreads: same-wave LDS ordering (lgkmcnt) is sufficient
    int l15 = lane & 15, l4 = lane >> 4;
    v8s af[4];
    #pragma unroll
    for (int kk = 0; kk < 4; ++kk)
        af[kk] = *reinterpret_cast<const v8s*>(&myet[l15][kk * 32 + l4 * 8]);

    size_t xabase = ((size_t)(b * NN + iA) * TT + t0) * CC;
    size_t xbbase = ((size_t)(b * NN + jA) * TT + t0) * CC;
    float s = 0.f, q = 0.f;
    #pragma unroll
    for (int nt = 0; nt < 8; ++nt) {
        int col = nt * 16 + l15;
        v4f acc = {};
        #pragma unroll
        for (int kk = 0; kk < 4; ++kk) {
            v8s bf = *reinterpret_cast<const v8s*>(Ebf + (size_t)col * 128 + kk * 32 + l4 * 8);
            acc = __builtin_amdgcn_mfma_f32_16x16x32_bf16(af[kk], bf, acc, 0, 0, 0);
        }
        #pragma unroll
        for (int reg = 0; reg < 4; ++reg) {
            int trow = l4 * 4 + reg;
            float xaf = bf2f(xAp[xabase + (size_t)trow * CC + col]);
            float xbf = bf2f(xBp[xbbase + (size_t)trow * CC + col]);
            float v = acc[reg] + xaf + xbf;
            s += v; q += v * v;
        }
    }
    #pragma unroll
    for (int off = 1; off < 64; off <<= 1) { s += __shfl_xor(s, off); q += __shfl_xor(q, off); }
    if (lane == 0) {
        atomicAdd(&epart[(size_t)(b * NE + e) * 2 + 0], s);
        atomicAdd(&epart[(size_t)(b * NE + e) * 2 + 1], q);
    }
}

// ---------------- reduce edge stats -> scale/shift ----------------
__global__ __launch_bounds__(64) void kRede(
    const float* __restrict__ epart, const float* __restrict__ g,
    const float* __restrict__ be, float* __restrict__ estats)
{
    int e = blockIdx.x;              // 0..143
    int tid = threadIdx.x;
    float s = 0.f, q = 0.f;
    if (tid < 16) {                  // 16 b partials
        s = epart[(size_t)(tid * NE + e) * 2 + 0];
        q = epart[(size_t)(tid * NE + e) * 2 + 1];
    }
    #pragma unroll
    for (int off = 1; off < 16; off <<= 1) { s += __shfl_xor(s, off); q += __shfl_xor(q, off); }
    if (tid == 0) {
        const float M = 262144.f;    // B*T*C
        float mean = s / M;
        float var = q / M - mean * mean;
        float sc = g[e] * rsqrtf(var + 1e-5f);
        estats[e * 2] = sc;
        estats[e * 2 + 1] = be[e] - mean * sc;
    }
}

// ---------------- C: recompute upd via MFMA + BN+relu+residual + softmax ----
template<bool OUT_F32>
__global__ __launch_bounds__(256, 4) void kC(
    unsigned short* __restrict__ ebf,          // bf16 edges (read; !OUT_F32: updated in place)
    float* __restrict__ eout,                  // f32 final edges (OUT_F32)
    const unsigned short* __restrict__ xAp, const unsigned short* __restrict__ xBp,
    const unsigned short* __restrict__ xV, const unsigned short* __restrict__ xU,
    const unsigned short* __restrict__ Ebf, const float* __restrict__ estats,
    unsigned short* __restrict__ yout, float* __restrict__ npart)
{
    __shared__ unsigned short et[48][136];
    __shared__ unsigned short xab[16][136];
    __shared__ unsigned short xv[12][136];
    __shared__ float2 scf[48];
    __shared__ float ns[4], nq[4];
    int tid = threadIdx.x;
    int bid = blockIdx.x;
    int third = bid % 3; int bt = bid / 3;
    int b = bt >> 7, t = bt & 127;
    if (tid < 48) scf[tid] = make_float2(estats[(third * 48 + tid) * 2],
                                         estats[(third * 48 + tid) * 2 + 1]);
    if (tid < 4) { ns[tid] = 0.f; nq[tid] = 0.f; }
    {   // stage xab: rows 0-3 = xA[third*4+row], rows 4-15 = xB[row-4]
        int row = tid >> 4, c8 = tid & 15;
        const unsigned short* src = (row < 4)
            ? (xAp + (((size_t)(b * NN + third * 4 + row) * TT) + t) * CC)
            : (xBp + (((size_t)(b * NN + (row - 4)) * TT) + t) * CC);
        *reinterpret_cast<v8s*>(&xab[row][c8 * 8]) = *reinterpret_cast<const v8s*>(src + c8 * 8);
    }
    if (tid < 192) {    // stage xV : 12 rows
        int row = tid >> 4, c8 = tid & 15;
        *reinterpret_cast<v8s*>(&xv[row][c8 * 8]) =
            *reinterpret_cast<const v8s*>(xV + (((size_t)(b * NN + row) * TT) + t) * CC + c8 * 8);
    }
    #pragma unroll
    for (int it = 0; it < 3; ++it) {    // stage 48 e-rows (256B each)
        int f = it * 256 + tid;
        int row = f >> 4, c8 = f & 15;
        *reinterpret_cast<v8s*>(&et[row][c8 * 8]) =
            *reinterpret_cast<const v8s*>(ebf + (((size_t)(b * NE + third * 48 + row) * TT) + t) * CC + c8 * 8);
    }
    __syncthreads();
    int lane = tid & 63, wid = tid >> 6;
    int l15 = lane & 15, l4 = lane >> 4;

    v8s bfr[2][4];
    #pragma unroll
    for (int nt2 = 0; nt2 < 2; ++nt2) {
        int col = (wid * 2 + nt2) * 16 + l15;
        #pragma unroll
        for (int kk = 0; kk < 4; ++kk)
            bfr[nt2][kk] = *reinterpret_cast<const v8s*>(Ebf + col * 128 + kk * 32 + l4 * 8);
    }
    v4f acc[3][2] = {};
    #pragma unroll
    for (int kk = 0; kk < 4; ++kk) {
        #pragma unroll
        for (int mt = 0; mt < 3; ++mt) {
            v8s a = *reinterpret_cast<const v8s*>(&et[mt * 16 + l15][kk * 32 + l4 * 8]);
            acc[mt][0] = __builtin_amdgcn_mfma_f32_16x16x32_bf16(a, bfr[0][kk], acc[mt][0], 0, 0, 0);
            acc[mt][1] = __builtin_amdgcn_mfma_f32_16x16x32_bf16(a, bfr[1][kk], acc[mt][1], 0, 0, 0);
        }
    }
    __syncthreads();    // all frag reads complete before et is overwritten
    // epilogue: upd = round(acc)+xa+xb; bn; en = e_old + relu(bn); et <- bf16(en)
    #pragma unroll
    for (int mt = 0; mt < 3; ++mt) {
        #pragma unroll
        for (int reg = 0; reg < 4; ++reg) {
            int r = mt * 16 + l4 * 4 + reg;      // local e row
            int il = r / 12, jl = r - il * 12;
            float2 sc = scf[r];
            #pragma unroll
            for (int nt2 = 0; nt2 < 2; ++nt2) {
                int col = (wid * 2 + nt2) * 16 + l15;
                float upd = rndbf(acc[mt][nt2][reg]) + bf2f(xab[il][col]) + bf2f(xab[4 + jl][col]);
                float bn = fmaxf(sc.x * upd + sc.y, 0.f);
                float en = bf2f(et[r][col]) + bn;
                et[r][col] = (unsigned short)f2bf(en);
            }
        }
    }
    __syncthreads();
    // coalesced writeback of new edges (bf16 in-place, or dense f32 final)
    #pragma unroll
    for (int it = 0; it < 3; ++it) {
        int f = it * 256 + tid;
        int row = f >> 4, c8 = f & 15;
        size_t goff = (((size_t)(b * NE + third * 48 + row) * TT) + t) * CC + c8 * 8;
        v8s nv = *reinterpret_cast<const v8s*>(&et[row][c8 * 8]);
        if constexpr (OUT_F32) {
            float4 o0, o1;
            o0.x = bf2f((unsigned short)nv[0]); o0.y = bf2f((unsigned short)nv[1]);
            o0.z = bf2f((unsigned short)nv[2]); o0.w = bf2f((unsigned short)nv[3]);
            o1.x = bf2f((unsigned short)nv[4]); o1.y = bf2f((unsigned short)nv[5]);
            o1.z = bf2f((unsigned short)nv[6]); o1.w = bf2f((unsigned short)nv[7]);
            *reinterpret_cast<float4*>(eout + goff)     = o0;
            *reinterpret_cast<float4*>(eout + goff + 4) = o1;
        } else {
            *reinterpret_cast<v8s*>(ebf + goff) = nv;
        }
    }
    // sigmoid -> softmax over j -> agg -> y + node stats
    #pragma unroll
    for (int ph = 0; ph < 2; ++ph) {
        int u = tid + ph * 256;          // 512 units = 4 i_loc * 128 c
        int il = u >> 7, c = u & 127;
        float den = 0.f, ag = 0.f;
        #pragma unroll
        for (int j = 0; j < 12; ++j) {
            float sv = bf2f(et[il * 12 + j][c]);
            float sg = 1.f / (1.f + __expf(-sv));
            float ev = __expf(sg);
            den += ev;
            ag += ev * bf2f(xv[j][c]);
        }
        float agg = ag / (den * 12.f);
        int i = third * 4 + il;
        size_t xa = (((size_t)(b * NN + i) * TT) + t) * CC + c;
        float yv = bf2f(xU[xa]) + agg;
        unsigned short us = (unsigned short)f2bf(yv);
        yout[xa] = us;
        float yr = bf2f(us);
        float s1 = yr, s2 = yr * yr;
        #pragma unroll
        for (int off = 1; off < 64; off <<= 1) { s1 += __shfl_xor(s1, off); s2 += __shfl_xor(s2, off); }
        if (lane == 0) { atomicAdd(&ns[il], s1); atomicAdd(&nq[il], s2); }
    }
    __syncthreads();
    if (tid < 4) {
        npart[(size_t)bid * 8 + tid * 2 + 0] = ns[tid];
        npart[(size_t)bid * 8 + tid * 2 + 1] = nq[tid];
    }
}

// ---------------- reduce node stats ----------------
__global__ __launch_bounds__(256) void kRedn(
    const float* __restrict__ npart, const float* __restrict__ g,
    const float* __restrict__ be, float* __restrict__ nstats)
{
    int n = blockIdx.x;             // 0..11
    int third = n >> 2, il = n & 3;
    float s = 0.f, q = 0.f;
    for (int bt = threadIdx.x; bt < 2048; bt += 256) {
        const float* p = npart + ((size_t)(bt * 3 + third) * 8 + il * 2);
        s += p[0]; q += p[1];
    }
    __shared__ float ss[4], qq[4];
    #pragma unroll
    for (int off = 32; off >= 1; off >>= 1) { s += __shfl_down(s, off); q += __shfl_down(q, off); }
    int wid = threadIdx.x >> 6;
    if ((threadIdx.x & 63) == 0) { ss[wid] = s; qq[wid] = q; }
    __syncthreads();
    if (threadIdx.x == 0) {
        s = ss[0] + ss[1] + ss[2] + ss[3];
        q = qq[0] + qq[1] + qq[2] + qq[3];
        const float M = 262144.f;   // B*T*C
        float mean = s / M;
        float var = q / M - mean * mean;
        float sc = g[n] * rsqrtf(var + 1e-5f);
        nstats[n * 2] = sc;
        nstats[n * 2 + 1] = be[n] - mean * sc;
    }
}

// ---------------- E: node BN + residual + relu ----------------
__global__ __launch_bounds__(256) void kE(
    const float* xres, const unsigned short* __restrict__ yin,
    const float* __restrict__ nstats, float* xout)
{
    int idx4 = blockIdx.x * 256 + threadIdx.x;     // 786432 float4s
    size_t base = (size_t)idx4 * 4;
    int n = (int)((base >> 14) % 12);
    float scv = nstats[n * 2], shv = nstats[n * 2 + 1];
    float4 xvv = *reinterpret_cast<const float4*>(xres + base);
    v4s yv4 = *reinterpret_cast<const v4s*>(yin + base);
    float4 o;
    o.x = fmaxf(xvv.x + scv * bf2f((unsigned short)yv4[0]) + shv, 0.f);
    o.y = fmaxf(xvv.y + scv * bf2f((unsigned short)yv4[1]) + shv, 0.f);
    o.z = fmaxf(xvv.z + scv * bf2f((unsigned short)yv4[2]) + shv, 0.f);
    o.w = fmaxf(xvv.w + scv * bf2f((unsigned short)yv4[3]) + shv, 0.f);
    *reinterpret_cast<float4*>(xout + base) = o;
}

extern "C" void kernel_launch(void* const* d_in, const int* in_sizes, int n_in,
                              void* d_out, int out_size, void* d_ws, size_t ws_size,
                              hipStream_t stream)
{
    const float* x0 = (const float*)d_in[0];
    const float* e0 = (const float*)d_in[1];
    const float* W[10];
    for (int i = 0; i < 10; ++i) W[i] = (const float*)d_in[2 + i];
    const float* ge1 = (const float*)d_in[12];
    const float* be1 = (const float*)d_in[13];
    const float* gv1 = (const float*)d_in[14];
    const float* bv1 = (const float*)d_in[15];
    const float* ge2 = (const float*)d_in[16];
    const float* be2 = (const float*)d_in[17];
    const float* gv2 = (const float*)d_in[18];
    const float* bv2 = (const float*)d_in[19];

    const size_t SZX = (size_t)BB * NN * TT * CC;   // 3145728
    const size_t SZE = (size_t)BB * NE * TT * CC;   // 37748736
    float* out_x = (float*)d_out;
    float* out_e = out_x + SZX;

    unsigned short* ws16 = (unsigned short*)d_ws;
    unsigned short* xA = ws16;
    unsigned short* xB = ws16 + SZX;
    unsigned short* xV = ws16 + 2 * SZX;
    unsigned short* xU = ws16 + 3 * SZX;
    unsigned short* yb = ws16 + 4 * SZX;
    unsigned short* ebf = ws16 + 5 * SZX;          // bf16 edge buffer
    float* epart  = (float*)(ebf + SZE);           // 2 layers * 2304 float2 = 9216 f
    float* estats = epart + 9216;                  // 288
    float* npart  = estats + 288;                  // 6144*8
    float* nstats = npart + 49152;                 // 24
    unsigned short* wb = (unsigned short*)(nstats + 24);   // 10*16384 bf16

    float* epart1 = epart;
    float* epart2 = epart + 4608;

    float* x1 = out_x;   // layer-1 x output (rewritten in-place by kE2)

    kW<<<640, 256, 0, stream>>>(W[0], W[1], W[2], W[3], W[4], W[5], W[6], W[7], W[8], W[9],
                                wb, epart);

    // ---- layer 1 ----
    kP<<<384, 256, 0, stream>>>(x0, wb, 0, 1, 4, 3, xA, xB, xV, xU);
    kA<true><<<4608, 256, 0, stream>>>(e0, nullptr, ebf, xA, xB, wb + 2 * 16384, epart1);
    kRede<<<144, 64, 0, stream>>>(epart1, ge1, be1, estats);
    kC<false><<<6144, 256, 0, stream>>>(ebf, nullptr, xA, xB, xV, xU,
                                        wb + 2 * 16384, estats, yb, npart);
    kRedn<<<12, 256, 0, stream>>>(npart, gv1, bv1, nstats);
    kE<<<3072, 256, 0, stream>>>(x0, yb, nstats, x1);

    // ---- layer 2 ----
    kP<<<384, 256, 0, stream>>>(x1, wb, 5, 6, 9, 8, xA, xB, xV, xU);
    kA<false><<<4608, 256, 0, stream>>>(nullptr, ebf, nullptr, xA, xB, wb + 7 * 16384, epart2);
    kRede<<<144, 64, 0, stream>>>(epart2, ge2, be2, estats);
    kC<true><<<6144, 256, 0, stream>>>(ebf, out_e, xA, xB, xV, xU,
                                       wb + 7 * 16384, estats, yb, npart);
    kRedn<<<12, 256, 0, stream>>>(npart, gv2, bv2, nstats);
    kE<<<3072, 256, 0, stream>>>(x1, yb, nstats, out_x);
}

// Round 17
// 270.822 us; speedup vs baseline: 1.5053x; 1.5053x over previous
//
#include <hip/hip_runtime.h>
#include <hip/hip_bf16.h>

#define BB 16
#define NN 12
#define NE 144
#define TT 128
#define CC 128

typedef __attribute__((ext_vector_type(8))) short v8s;   // 8 x bf16
typedef __attribute__((ext_vector_type(4))) short v4s;   // 4 x bf16
typedef __attribute__((ext_vector_type(4))) float v4f;   // mfma accumulator

__device__ __forceinline__ short f2bf(float f) {
    unsigned u = __float_as_uint(f);
    u += 0x7fffu + ((u >> 16) & 1u);        // RNE
    return (short)(u >> 16);
}
__device__ __forceinline__ float bf2f(unsigned short u) {
    return __uint_as_float(((unsigned)u) << 16);
}
__device__ __forceinline__ float rndbf(float f) { return bf2f((unsigned short)f2bf(f)); }
__device__ __forceinline__ v4s f4_to_bf4(float4 a) {
    v4s r; r[0] = f2bf(a.x); r[1] = f2bf(a.y); r[2] = f2bf(a.z); r[3] = f2bf(a.w); return r;
}

// ---------------- weights -> bf16 ----------------
__global__ __launch_bounds__(256) void kW(
    const float* A1, const float* B1, const float* E1, const float* U1, const float* V1,
    const float* A2, const float* B2, const float* E2, const float* U2, const float* V2,
    unsigned short* wb)
{
    int idx = blockIdx.x * 256 + threadIdx.x;   // 10*16384
    int w = idx >> 14, r = idx & 16383;
    const float* s;
    switch (w) {
        case 0: s = A1; break; case 1: s = B1; break; case 2: s = E1; break;
        case 3: s = U1; break; case 4: s = V1; break; case 5: s = A2; break;
        case 6: s = B2; break; case 7: s = E2; break; case 8: s = U2; break;
        default: s = V2; break;
    }
    wb[idx] = (unsigned short)f2bf(s[r]);
}

// ---------------- P: x @ {A,B,V,U}^T  -> bf16 outputs ----------------
__global__ __launch_bounds__(256) void kP(
    const float* __restrict__ x, const unsigned short* __restrict__ wb,
    int sA, int sB, int sV, int sU,
    unsigned short* __restrict__ oA, unsigned short* __restrict__ oB,
    unsigned short* __restrict__ oV, unsigned short* __restrict__ oU)
{
    __shared__ unsigned short xt[64][136];
    int tid = threadIdx.x;
    int m0 = blockIdx.x * 64;
    #pragma unroll
    for (int it = 0; it < 8; ++it) {
        int f = it * 256 + tid;
        int row = f >> 5, c4 = f & 31;
        float4 v = *reinterpret_cast<const float4*>(x + (size_t)m0 * 128 + (size_t)f * 4);
        *reinterpret_cast<v4s*>(&xt[row][c4 * 4]) = f4_to_bf4(v);
    }
    __syncthreads();
    int lane = tid & 63, wid = tid >> 6;
    int l15 = lane & 15, l4 = lane >> 4;

    const unsigned short* Ws[4] = { wb + (size_t)sA * 16384, wb + (size_t)sB * 16384,
                                    wb + (size_t)sV * 16384, wb + (size_t)sU * 16384 };
    unsigned short* Os[4] = { oA, oB, oV, oU };

    #pragma unroll
    for (int w = 0; w < 4; ++w) {
        const unsigned short* W = Ws[w];
        unsigned short* out = Os[w];
        v8s bfr[2][4];
        #pragma unroll
        for (int nt2 = 0; nt2 < 2; ++nt2) {
            int col = (wid * 2 + nt2) * 16 + l15;
            #pragma unroll
            for (int kk = 0; kk < 4; ++kk)
                bfr[nt2][kk] = *reinterpret_cast<const v8s*>(W + col * 128 + kk * 32 + l4 * 8);
        }
        v4f acc[4][2] = {};
        #pragma unroll
        for (int kk = 0; kk < 4; ++kk) {
            #pragma unroll
            for (int mt = 0; mt < 4; ++mt) {
                v8s a = *reinterpret_cast<const v8s*>(&xt[mt * 16 + l15][kk * 32 + l4 * 8]);
                acc[mt][0] = __builtin_amdgcn_mfma_f32_16x16x32_bf16(a, bfr[0][kk], acc[mt][0], 0, 0, 0);
                acc[mt][1] = __builtin_amdgcn_mfma_f32_16x16x32_bf16(a, bfr[1][kk], acc[mt][1], 0, 0, 0);
            }
        }
        #pragma unroll
        for (int mt = 0; mt < 4; ++mt) {
            #pragma unroll
            for (int nt2 = 0; nt2 < 2; ++nt2) {
                int col = (wid * 2 + nt2) * 16 + l15;
                #pragma unroll
                for (int reg = 0; reg < 4; ++reg) {
                    int rowg = m0 + mt * 16 + l4 * 4 + reg;
                    out[(size_t)rowg * 128 + col] = (unsigned short)f2bf(acc[mt][nt2][reg]);
                }
            }
        }
    }
}

// ---------------- A: edge_upd stats, 2-barrier register-stats form ----------------
template<bool IN_F32>
__global__ __launch_bounds__(256, 4) void kA(
    const float* __restrict__ ef32, const unsigned short* __restrict__ ebf_in,
    unsigned short* __restrict__ ebf_out,
    const unsigned short* __restrict__ xAp, const unsigned short* __restrict__ xBp,
    const unsigned short* __restrict__ Ebf, float2* __restrict__ epart)
{
    __shared__ unsigned short et[64][136];
    __shared__ unsigned short xs[64][136];
    __shared__ float sblk[2];
    int tid = threadIdx.x;
    int bid = blockIdx.x;
    int th = bid & 1; int m = bid >> 1;
    int e = m % NE, b = m / NE;
    int iA = e / 12, jA = e - iA * 12;
    int t0 = th * 64;
    if (tid < 2) sblk[tid] = 0.f;
    size_t erow0 = ((size_t)(b * NE + e) * TT + t0) * CC;

    // stage xs = bf16(xa + xb), coalesced
    size_t xaoff = ((size_t)(b * NN + iA) * TT + t0) * CC;
    size_t xboff = ((size_t)(b * NN + jA) * TT + t0) * CC;
    #pragma unroll
    for (int it = 0; it < 4; ++it) {
        int f = it * 256 + tid;
        int row = f >> 4, c8 = f & 15;
        v8s xa = *reinterpret_cast<const v8s*>(xAp + xaoff + (size_t)row * CC + c8 * 8);
        v8s xb = *reinterpret_cast<const v8s*>(xBp + xboff + (size_t)row * CC + c8 * 8);
        v8s sv;
        #pragma unroll
        for (int k = 0; k < 8; ++k)
            sv[k] = f2bf(bf2f((unsigned short)xa[k]) + bf2f((unsigned short)xb[k]));
        *reinterpret_cast<v8s*>(&xs[row][c8 * 8]) = sv;
    }
    // stage edge tile (and bf16 conversion write for layer 1)
    if constexpr (IN_F32) {
        #pragma unroll
        for (int it = 0; it < 8; ++it) {
            int f = it * 256 + tid;           // 2048 float4 = 64x128 f32
            int row = f >> 5, c4 = f & 31;
            // e0 is read exactly once -> nontemporal (don't pollute L2/L3)
            v4f v = __builtin_nontemporal_load(
                reinterpret_cast<const v4f*>(ef32 + erow0 + (size_t)row * CC + c4 * 4));
            v4s bv;
            bv[0] = f2bf(v[0]); bv[1] = f2bf(v[1]); bv[2] = f2bf(v[2]); bv[3] = f2bf(v[3]);
            *reinterpret_cast<v4s*>(&et[row][c4 * 4]) = bv;
            *reinterpret_cast<v4s*>(ebf_out + erow0 + (size_t)row * CC + c4 * 4) = bv;
        }
    } else {
        #pragma unroll
        for (int it = 0; it < 4; ++it) {
            int f = it * 256 + tid;           // 1024 v8s
            int row = f >> 4, c8 = f & 15;
            *reinterpret_cast<v8s*>(&et[row][c8 * 8]) =
                *reinterpret_cast<const v8s*>(ebf_in + erow0 + (size_t)row * CC + c8 * 8);
        }
    }
    __syncthreads();

    int lane = tid & 63, wid = tid >> 6;
    int l15 = lane & 15, l4 = lane >> 4;

    v8s bfr[2][4];
    #pragma unroll
    for (int nt2 = 0; nt2 < 2; ++nt2) {
        int col = (wid * 2 + nt2) * 16 + l15;
        #pragma unroll
        for (int kk = 0; kk < 4; ++kk)
            bfr[nt2][kk] = *reinterpret_cast<const v8s*>(Ebf + col * 128 + kk * 32 + l4 * 8);
    }
    v4f acc[4][2] = {};
    #pragma unroll
    for (int kk = 0; kk < 4; ++kk) {
        #pragma unroll
        for (int mt = 0; mt < 4; ++mt) {
            v8s a = *reinterpret_cast<const v8s*>(&et[mt * 16 + l15][kk * 32 + l4 * 8]);
            acc[mt][0] = __builtin_amdgcn_mfma_f32_16x16x32_bf16(a, bfr[0][kk], acc[mt][0], 0, 0, 0);
            acc[mt][1] = __builtin_amdgcn_mfma_f32_16x16x32_bf16(a, bfr[1][kk], acc[mt][1], 0, 0, 0);
        }
    }
    // stats straight from acc regs: v = rndbf(acc) + xs[row][col]
    float s = 0.f, q = 0.f;
    #pragma unroll
    for (int mt = 0; mt < 4; ++mt) {
        #pragma unroll
        for (int nt2 = 0; nt2 < 2; ++nt2) {
            int col = (wid * 2 + nt2) * 16 + l15;
            #pragma unroll
            for (int reg = 0; reg < 4; ++reg) {
                int row = mt * 16 + l4 * 4 + reg;
                float v = rndbf(acc[mt][nt2][reg]) + bf2f(xs[row][col]);
                s += v; q += v * v;
            }
        }
    }
    #pragma unroll
    for (int off = 1; off < 64; off <<= 1) { s += __shfl_xor(s, off); q += __shfl_xor(q, off); }
    if (lane == 0) { atomicAdd(&sblk[0], s); atomicAdd(&sblk[1], q); }
    __syncthreads();
    if (tid == 0) epart[bid] = make_float2(sblk[0], sblk[1]);
}

// ---------------- reduce edge stats -> scale/shift ----------------
__global__ __launch_bounds__(64) void kRede(
    const float2* __restrict__ epart, const float* __restrict__ g,
    const float* __restrict__ be, float* __restrict__ estats)
{
    int e = blockIdx.x;              // 0..143
    int tid = threadIdx.x;
    float s = 0.f, q = 0.f;
    if (tid < 32) {                  // 16 b * 2 th partials
        int b = tid >> 1, th = tid & 1;
        float2 p = epart[(size_t)(b * NE + e) * 2 + th];
        s = p.x; q = p.y;
    }
    #pragma unroll
    for (int off = 1; off < 32; off <<= 1) { s += __shfl_xor(s, off); q += __shfl_xor(q, off); }
    if (tid == 0) {
        const float M = 262144.f;    // B*T*C
        float mean = s / M;
        float var = q / M - mean * mean;
        float sc = g[e] * rsqrtf(var + 1e-5f);
        estats[e * 2] = sc;
        estats[e * 2 + 1] = be[e] - mean * sc;
    }
}

// ---------------- C: recompute upd via MFMA + BN+relu+residual + softmax ----
// Block = (b, t, third): 48 e-rows x 128 c tile at one t.
template<bool OUT_F32>
__global__ __launch_bounds__(256, 4) void kC(
    unsigned short* __restrict__ ebf,          // bf16 edges (read; !OUT_F32: updated in place)
    float* __restrict__ eout,                  // f32 final edges (OUT_F32)
    const unsigned short* __restrict__ xAp, const unsigned short* __restrict__ xBp,
    const unsigned short* __restrict__ xV, const unsigned short* __restrict__ xU,
    const unsigned short* __restrict__ Ebf, const float* __restrict__ estats,
    unsigned short* __restrict__ yout, float* __restrict__ npart)
{
    __shared__ unsigned short et[48][136];
    __shared__ unsigned short xab[16][136];
    __shared__ unsigned short xv[12][136];
    __shared__ float2 scf[48];
    __shared__ float ns[4], nq[4];
    int tid = threadIdx.x;
    int bid = blockIdx.x;
    int third = bid % 3; int bt = bid / 3;
    int b = bt >> 7, t = bt & 127;
    if (tid < 48) scf[tid] = make_float2(estats[(third * 48 + tid) * 2],
                                         estats[(third * 48 + tid) * 2 + 1]);
    if (tid < 4) { ns[tid] = 0.f; nq[tid] = 0.f; }
    {   // stage xab: rows 0-3 = xA[third*4+row], rows 4-15 = xB[row-4]
        int row = tid >> 4, c8 = tid & 15;
        const unsigned short* src = (row < 4)
            ? (xAp + (((size_t)(b * NN + third * 4 + row) * TT) + t) * CC)
            : (xBp + (((size_t)(b * NN + (row - 4)) * TT) + t) * CC);
        *reinterpret_cast<v8s*>(&xab[row][c8 * 8]) = *reinterpret_cast<const v8s*>(src + c8 * 8);
    }
    if (tid < 192) {    // stage xV : 12 rows
        int row = tid >> 4, c8 = tid & 15;
        *reinterpret_cast<v8s*>(&xv[row][c8 * 8]) =
            *reinterpret_cast<const v8s*>(xV + (((size_t)(b * NN + row) * TT) + t) * CC + c8 * 8);
    }
    #pragma unroll
    for (int it = 0; it < 3; ++it) {    // stage 48 e-rows (256B each)
        int f = it * 256 + tid;
        int row = f >> 4, c8 = f & 15;
        *reinterpret_cast<v8s*>(&et[row][c8 * 8]) =
            *reinterpret_cast<const v8s*>(ebf + (((size_t)(b * NE + third * 48 + row) * TT) + t) * CC + c8 * 8);
    }
    __syncthreads();
    int lane = tid & 63, wid = tid >> 6;
    int l15 = lane & 15, l4 = lane >> 4;

    v8s bfr[2][4];
    #pragma unroll
    for (int nt2 = 0; nt2 < 2; ++nt2) {
        int col = (wid * 2 + nt2) * 16 + l15;
        #pragma unroll
        for (int kk = 0; kk < 4; ++kk)
            bfr[nt2][kk] = *reinterpret_cast<const v8s*>(Ebf + col * 128 + kk * 32 + l4 * 8);
    }
    v4f acc[3][2] = {};
    #pragma unroll
    for (int kk = 0; kk < 4; ++kk) {
        #pragma unroll
        for (int mt = 0; mt < 3; ++mt) {
            v8s a = *reinterpret_cast<const v8s*>(&et[mt * 16 + l15][kk * 32 + l4 * 8]);
            acc[mt][0] = __builtin_amdgcn_mfma_f32_16x16x32_bf16(a, bfr[0][kk], acc[mt][0], 0, 0, 0);
            acc[mt][1] = __builtin_amdgcn_mfma_f32_16x16x32_bf16(a, bfr[1][kk], acc[mt][1], 0, 0, 0);
        }
    }
    __syncthreads();    // all frag reads complete before et is overwritten
    // epilogue: upd = round(acc)+xa+xb; bn; en = e_old + relu(bn); et <- bf16(en)
    #pragma unroll
    for (int mt = 0; mt < 3; ++mt) {
        #pragma unroll
        for (int reg = 0; reg < 4; ++reg) {
            int r = mt * 16 + l4 * 4 + reg;      // local e row
            int il = r / 12, jl = r - il * 12;
            float2 sc = scf[r];
            #pragma unroll
            for (int nt2 = 0; nt2 < 2; ++nt2) {
                int col = (wid * 2 + nt2) * 16 + l15;
                float upd = rndbf(acc[mt][nt2][reg]) + bf2f(xab[il][col]) + bf2f(xab[4 + jl][col]);
                float bn = fmaxf(sc.x * upd + sc.y, 0.f);
                float en = bf2f(et[r][col]) + bn;
                et[r][col] = (unsigned short)f2bf(en);
                if constexpr (OUT_F32) {
                    int eg = third * 48 + r;
                    // final f32 edges are never re-read -> nontemporal store
                    __builtin_nontemporal_store(
                        en, eout + (((size_t)(b * NE + eg) * TT) + t) * CC + col);
                }
            }
        }
    }
    __syncthreads();
    if constexpr (!OUT_F32) {   // coalesced bf16 writeback of new edges
        #pragma unroll
        for (int it = 0; it < 3; ++it) {
            int f = it * 256 + tid;
            int row = f >> 4, c8 = f & 15;
            *reinterpret_cast<v8s*>(ebf + (((size_t)(b * NE + third * 48 + row) * TT) + t) * CC + c8 * 8) =
                *reinterpret_cast<const v8s*>(&et[row][c8 * 8]);
        }
    }
    // sigmoid -> softmax over j -> agg -> y + node stats
    #pragma unroll
    for (int ph = 0; ph < 2; ++ph) {
        int u = tid + ph * 256;          // 512 units = 4 i_loc * 128 c
        int il = u >> 7, c = u & 127;
        float den = 0.f, ag = 0.f;
        #pragma unroll
        for (int j = 0; j < 12; ++j) {
            float sv = bf2f(et[il * 12 + j][c]);
            float sg = 1.f / (1.f + __expf(-sv));
            float ev = __expf(sg);
            den += ev;
            ag += ev * bf2f(xv[j][c]);
        }
        float agg = ag / (den * 12.f);
        int i = third * 4 + il;
        size_t xa = (((size_t)(b * NN + i) * TT) + t) * CC + c;
        float yv = bf2f(xU[xa]) + agg;
        unsigned short us = (unsigned short)f2bf(yv);
        yout[xa] = us;
        float yr = bf2f(us);
        float s1 = yr, s2 = yr * yr;
        #pragma unroll
        for (int off = 1; off < 64; off <<= 1) { s1 += __shfl_xor(s1, off); s2 += __shfl_xor(s2, off); }
        if (lane == 0) { atomicAdd(&ns[il], s1); atomicAdd(&nq[il], s2); }
    }
    __syncthreads();
    if (tid < 4) {
        npart[(size_t)bid * 8 + tid * 2 + 0] = ns[tid];
        npart[(size_t)bid * 8 + tid * 2 + 1] = nq[tid];
    }
}

// ---------------- reduce node stats ----------------
__global__ __launch_bounds__(256) void kRedn(
    const float* __restrict__ npart, const float* __restrict__ g,
    const float* __restrict__ be, float* __restrict__ nstats)
{
    int n = blockIdx.x;             // 0..11
    int third = n >> 2, il = n & 3;
    float s = 0.f, q = 0.f;
    for (int bt = threadIdx.x; bt < 2048; bt += 256) {
        const float* p = npart + ((size_t)(bt * 3 + third) * 8 + il * 2);
        s += p[0]; q += p[1];
    }
    __shared__ float ss[4], qq[4];
    #pragma unroll
    for (int off = 32; off >= 1; off >>= 1) { s += __shfl_down(s, off); q += __shfl_down(q, off); }
    int wid = threadIdx.x >> 6;
    if ((threadIdx.x & 63) == 0) { ss[wid] = s; qq[wid] = q; }
    __syncthreads();
    if (threadIdx.x == 0) {
        s = ss[0] + ss[1] + ss[2] + ss[3];
        q = qq[0] + qq[1] + qq[2] + qq[3];
        const float M = 262144.f;   // B*T*C
        float mean = s / M;
        float var = q / M - mean * mean;
        float sc = g[n] * rsqrtf(var + 1e-5f);
        nstats[n * 2] = sc;
        nstats[n * 2 + 1] = be[n] - mean * sc;
    }
}

// ---------------- E: node BN + residual + relu ----------------
__global__ __launch_bounds__(256) void kE(
    const float* xres, const unsigned short* __restrict__ yin,
    const float* __restrict__ nstats, float* xout)
{
    int idx4 = blockIdx.x * 256 + threadIdx.x;     // 786432 float4s
    size_t base = (size_t)idx4 * 4;
    int n = (int)((base >> 14) % 12);
    float scv = nstats[n * 2], shv = nstats[n * 2 + 1];
    float4 xvv = *reinterpret_cast<const float4*>(xres + base);
    v4s yv4 = *reinterpret_cast<const v4s*>(yin + base);
    float4 o;
    o.x = fmaxf(xvv.x + scv * bf2f((unsigned short)yv4[0]) + shv, 0.f);
    o.y = fmaxf(xvv.y + scv * bf2f((unsigned short)yv4[1]) + shv, 0.f);
    o.z = fmaxf(xvv.z + scv * bf2f((unsigned short)yv4[2]) + shv, 0.f);
    o.w = fmaxf(xvv.w + scv * bf2f((unsigned short)yv4[3]) + shv, 0.f);
    *reinterpret_cast<float4*>(xout + base) = o;
}

extern "C" void kernel_launch(void* const* d_in, const int* in_sizes, int n_in,
                              void* d_out, int out_size, void* d_ws, size_t ws_size,
                              hipStream_t stream)
{
    const float* x0 = (const float*)d_in[0];
    const float* e0 = (const float*)d_in[1];
    const float* W[10];
    for (int i = 0; i < 10; ++i) W[i] = (const float*)d_in[2 + i];
    const float* ge1 = (const float*)d_in[12];
    const float* be1 = (const float*)d_in[13];
    const float* gv1 = (const float*)d_in[14];
    const float* bv1 = (const float*)d_in[15];
    const float* ge2 = (const float*)d_in[16];
    const float* be2 = (const float*)d_in[17];
    const float* gv2 = (const float*)d_in[18];
    const float* bv2 = (const float*)d_in[19];

    const size_t SZX = (size_t)BB * NN * TT * CC;   // 3145728
    const size_t SZE = (size_t)BB * NE * TT * CC;   // 37748736
    float* out_x = (float*)d_out;
    float* out_e = out_x + SZX;

    unsigned short* ws16 = (unsigned short*)d_ws;
    unsigned short* xA = ws16;
    unsigned short* xB = ws16 + SZX;
    unsigned short* xV = ws16 + 2 * SZX;
    unsigned short* xU = ws16 + 3 * SZX;
    unsigned short* yb = ws16 + 4 * SZX;
    unsigned short* ebf = ws16 + 5 * SZX;          // bf16 edge buffer
    float2* epart  = (float2*)(ebf + SZE);         // 4608 float2
    float* estats = (float*)(epart + 4608);        // 288
    float* npart  = estats + 288;                  // 6144*8
    float* nstats = npart + 49152;                 // 24
    unsigned short* wb = (unsigned short*)(nstats + 24);   // 10*16384 bf16

    float* x1 = out_x;   // layer-1 x output (rewritten in-place by kE2)

    kW<<<640, 256, 0, stream>>>(W[0], W[1], W[2], W[3], W[4], W[5], W[6], W[7], W[8], W[9], wb);

    // ---- layer 1 ----
    kP<<<384, 256, 0, stream>>>(x0, wb, 0, 1, 4, 3, xA, xB, xV, xU);
    kA<true><<<4608, 256, 0, stream>>>(e0, nullptr, ebf, xA, xB, wb + 2 * 16384, epart);
    kRede<<<144, 64, 0, stream>>>(epart, ge1, be1, estats);
    kC<false><<<6144, 256, 0, stream>>>(ebf, nullptr, xA, xB, xV, xU,
                                        wb + 2 * 16384, estats, yb, npart);
    kRedn<<<12, 256, 0, stream>>>(npart, gv1, bv1, nstats);
    kE<<<3072, 256, 0, stream>>>(x0, yb, nstats, x1);

    // ---- layer 2 ----
    kP<<<384, 256, 0, stream>>>(x1, wb, 5, 6, 9, 8, xA, xB, xV, xU);
    kA<false><<<4608, 256, 0, stream>>>(nullptr, ebf, nullptr, xA, xB, wb + 7 * 16384, epart);
    kRede<<<144, 64, 0, stream>>>(epart, ge2, be2, estats);
    kC<true><<<6144, 256, 0, stream>>>(ebf, out_e, xA, xB, xV, xU,
                                       wb + 7 * 16384, estats, yb, npart);
    kRedn<<<12, 256, 0, stream>>>(npart, gv2, bv2, nstats);
    kE<<<3072, 256, 0, stream>>>(x1, yb, nstats, out_x);
}